// Round 4
// baseline (223.371 us; speedup 1.0000x reference)
//
#include <hip/hip_runtime.h>

#define T_SEQ 2048
#define C_DIM 128
#define S_QK 0.08838834764831845f

typedef __attribute__((ext_vector_type(8))) short bf16x8;
typedef __attribute__((ext_vector_type(4))) float f32x4;

// ---- workspace layout ----
// qw  bf16 [8][2048][128]    @ 0
// kw  bf16 [8][2048][128]    @ 4,194,304
// vw  bf16 [8][128][2048]    @ 8,388,608   (V^T)
// opart bf16 [1120][64][128] @ 12,582,912  (18,350,080 B)
// ml  float2 [1120][64]      @ 30,932,992  (573,440 B)    total ~31.5 MB
#define ML_OFF 30932992UL

__device__ __forceinline__ unsigned short f2bf(float f) {
    union { float f; unsigned int u; } v; v.f = f;
    unsigned int r = v.u + 0x7FFFu + ((v.u >> 16) & 1u);
    return (unsigned short)(r >> 16);
}

__device__ __forceinline__ bf16x8 cvt8(const float4 lo, const float4 hi, float s) {
    bf16x8 r;
    r[0] = (short)f2bf(lo.x * s); r[1] = (short)f2bf(lo.y * s);
    r[2] = (short)f2bf(lo.z * s); r[3] = (short)f2bf(lo.w * s);
    r[4] = (short)f2bf(hi.x * s); r[5] = (short)f2bf(hi.y * s);
    r[6] = (short)f2bf(hi.z * s); r[7] = (short)f2bf(hi.w * s);
    return r;
}

// slot base within a batch for qt>=4, chunks of 4 key-tiles (140 slots/batch)
__device__ __forceinline__ int chunk_base4(int qt) {
    int g = qt >> 2;                       // 1..7
    return 2 * (g - 1) * (g + 2) + (qt - 4 * g) * (g + 1);
}

// ---------------------------------------------------------------------------
// proj: barrier-free. A/B fragments loaded directly from fp32 global and
// converted in registers (scale folded into Wq cvt). grid (256, 3), 4
// independent waves/block, each owning a 16-row strip.
// ---------------------------------------------------------------------------
__global__ __launch_bounds__(256, 4) void proj_kernel(
    const float* __restrict__ x,
    const float* __restrict__ Wq, const float* __restrict__ Wk,
    const float* __restrict__ Wv,
    unsigned short* __restrict__ qo, unsigned short* __restrict__ ko,
    unsigned short* __restrict__ vto)
{
    const int rt = blockIdx.x;             // 64-row tile over B*T
    const int z  = blockIdx.y;             // 0=q, 1=k, 2=v(transposed)
    const int tid  = threadIdx.x;
    const int lane = tid & 63;
    const int w    = tid >> 6;
    const int n16  = lane & 15;
    const int quad = lane >> 4;

    // per-wave epilogue staging: max(16*128, 128*18) = 2304 shorts
    __shared__ __align__(16) unsigned short OS[4][2304];     // 18432 B

    const float* W = (z == 0) ? Wq : (z == 1) ? Wk : Wv;
    const float scale = (z == 0) ? S_QK : 1.0f;

    // A fragments: 16 rows of x, direct fp32 load + cvt
    const float* xr = x + (size_t)(rt * 64 + w * 16 + n16) * C_DIM;
    bf16x8 a[4];
    #pragma unroll
    for (int kk = 0; kk < 4; ++kk) {
        const float* p = xr + kk * 32 + quad * 8;
        a[kk] = cvt8(*reinterpret_cast<const float4*>(p),
                     *reinterpret_cast<const float4*>(p + 4), 1.0f);
    }

    f32x4 acc[8];
    #pragma unroll
    for (int nt = 0; nt < 8; ++nt) acc[nt] = (f32x4){0.f, 0.f, 0.f, 0.f};

    #pragma unroll
    for (int kk = 0; kk < 4; ++kk)
        #pragma unroll
        for (int nt = 0; nt < 8; ++nt) {
            const float* wp = W + (size_t)(nt * 16 + n16) * C_DIM + kk * 32 + quad * 8;
            bf16x8 bfr = cvt8(*reinterpret_cast<const float4*>(wp),
                              *reinterpret_cast<const float4*>(wp + 4), scale);
            acc[nt] = __builtin_amdgcn_mfma_f32_16x16x32_bf16(a[kk], bfr, acc[nt], 0, 0, 0);
        }

    unsigned short* os = OS[w];
    if (z < 2) {
        // stage wave's 16x128 output, then contiguous uint4 stores
        #pragma unroll
        for (int nt = 0; nt < 8; ++nt)
            #pragma unroll
            for (int r = 0; r < 4; ++r)
                os[(quad * 4 + r) * 128 + nt * 16 + n16] = f2bf(acc[nt][r]);
        unsigned short* dst = (z == 0 ? qo : ko) + (size_t)(rt * 64 + w * 16) * C_DIM;
        #pragma unroll
        for (int i = 0; i < 4; ++i) {
            int e = (lane + i * 64) * 8;   // 2048 shorts contiguous
            *reinterpret_cast<uint4*>(dst + e) =
                *reinterpret_cast<const uint4*>(os + e);
        }
    } else {
        // transpose: stage [128 d][16 t] (stride 18), store 16-B chunks
        #pragma unroll
        for (int nt = 0; nt < 8; ++nt)
            #pragma unroll
            for (int r = 0; r < 4; ++r)
                os[(nt * 16 + n16) * 18 + quad * 4 + r] = f2bf(acc[nt][r]);
        const int b = rt >> 5;
        const int t_in_b = (rt & 31) * 64 + w * 16;
        unsigned short* dst = vto + (size_t)b * C_DIM * T_SEQ + t_in_b;
        #pragma unroll
        for (int i = 0; i < 4; ++i) {
            int e = lane + i * 64;         // 256 chunks: (d, half)
            int d = e >> 1, half = (e & 1) * 8;
            *reinterpret_cast<uint4*>(dst + (size_t)d * T_SEQ + half) =
                *reinterpret_cast<const uint4*>(os + d * 18 + half);
        }
    }
}

// ---------------------------------------------------------------------------
// attn pass 1: barrier-free split-K flash attention. grid (32, 8, 8),
// 4 independent waves/block. K and V^T fragments loaded directly from
// global in MFMA B-layout (no LDS staging, no __syncthreads).
// ---------------------------------------------------------------------------
__global__ __launch_bounds__(256, 4) void attn_kernel(
    const unsigned short* __restrict__ qb,
    const unsigned short* __restrict__ kb,
    const unsigned short* __restrict__ vtb,
    unsigned short* __restrict__ opart, float2* __restrict__ mlbuf,
    float* __restrict__ out)
{
    const int qt    = blockIdx.x;
    const int chunk = blockIdx.y;
    const int b     = blockIdx.z;
    if (chunk * 4 > qt) return;

    const int tid  = threadIdx.x;
    const int lane = tid & 63;
    const int w    = tid >> 6;
    const int n16  = lane & 15;
    const int quad = lane >> 4;

    __shared__ __align__(16) unsigned short Pl[4][16 * 72];   //  9216 B
    __shared__ __align__(16) unsigned short OS[4][16 * 128];  // 16384 B

    const size_t bT = (size_t)b * T_SEQ;
    const int qbase = qt * 64 + w * 16;

    bf16x8 qfr[4];
    #pragma unroll
    for (int kk = 0; kk < 4; ++kk)
        qfr[kk] = *reinterpret_cast<const bf16x8*>(
            qb + (bT + qbase + n16) * C_DIM + kk * 32 + quad * 8);

    f32x4 o[8];
    #pragma unroll
    for (int ct = 0; ct < 8; ++ct) o[ct] = (f32x4){0.f, 0.f, 0.f, 0.f};
    float m[4], l[4];
    #pragma unroll
    for (int r = 0; r < 4; ++r) { m[r] = -INFINITY; l[r] = 0.f; }

    const int k0 = chunk * 4;
    const int k1 = min(k0 + 4, qt + 1);
    const unsigned short* vbase = vtb + (size_t)b * C_DIM * T_SEQ;

    for (int kt = k0; kt < k1; ++kt) {
        // ---- S = Q K^T, K fragments direct from global ----
        const unsigned short* kp = kb + (bT + (size_t)kt * 64) * C_DIM;
        f32x4 s[4];
        #pragma unroll
        for (int nt = 0; nt < 4; ++nt) s[nt] = (f32x4){0.f, 0.f, 0.f, 0.f};
        #pragma unroll
        for (int kk = 0; kk < 4; ++kk)
            #pragma unroll
            for (int nt = 0; nt < 4; ++nt) {
                bf16x8 kf = *reinterpret_cast<const bf16x8*>(
                    kp + (nt * 16 + n16) * C_DIM + kk * 32 + quad * 8);
                s[nt] = __builtin_amdgcn_mfma_f32_16x16x32_bf16(qfr[kk], kf, s[nt], 0, 0, 0);
            }

        if (kt == qt) {                    // causal mask on diagonal tile
            #pragma unroll
            for (int nt = 0; nt < 4; ++nt)
                #pragma unroll
                for (int r = 0; r < 4; ++r) {
                    int sabs = kt * 64 + nt * 16 + n16;
                    int qabs = qbase + quad * 4 + r;
                    if (sabs > qabs) s[nt][r] = -1e30f;
                }
        }

        // ---- online softmax ----
        float alpha[4];
        #pragma unroll
        for (int r = 0; r < 4; ++r) {
            float tmax = fmaxf(fmaxf(s[0][r], s[1][r]), fmaxf(s[2][r], s[3][r]));
            #pragma unroll
            for (int off = 1; off < 16; off <<= 1)
                tmax = fmaxf(tmax, __shfl_xor(tmax, off));
            float mn = fmaxf(m[r], tmax);
            alpha[r] = __expf(m[r] - mn);
            float tsum = 0.f;
            #pragma unroll
            for (int nt = 0; nt < 4; ++nt) {
                float p = __expf(s[nt][r] - mn);
                s[nt][r] = p;
                tsum += p;
            }
            #pragma unroll
            for (int off = 1; off < 16; off <<= 1)
                tsum += __shfl_xor(tsum, off);
            l[r] = l[r] * alpha[r] + tsum;
            m[r] = mn;
        }
        #pragma unroll
        for (int ct = 0; ct < 8; ++ct)
            #pragma unroll
            for (int r = 0; r < 4; ++r)
                o[ct][r] *= alpha[r];

        // ---- P: C-layout -> per-wave LDS -> A-layout ----
        unsigned short* pw = Pl[w];
        #pragma unroll
        for (int nt = 0; nt < 4; ++nt)
            #pragma unroll
            for (int r = 0; r < 4; ++r)
                pw[(quad * 4 + r) * 72 + nt * 16 + n16] = f2bf(s[nt][r]);

        // ---- O += P V, V^T fragments direct from global ----
        const unsigned short* vp = vbase + (size_t)kt * 64;
        #pragma unroll
        for (int kk2 = 0; kk2 < 2; ++kk2) {
            bf16x8 afr = *reinterpret_cast<const bf16x8*>(
                &pw[n16 * 72 + kk2 * 32 + quad * 8]);
            #pragma unroll
            for (int ct = 0; ct < 8; ++ct) {
                bf16x8 vf = *reinterpret_cast<const bf16x8*>(
                    vp + (size_t)(ct * 16 + n16) * T_SEQ + kk2 * 32 + quad * 8);
                o[ct] = __builtin_amdgcn_mfma_f32_16x16x32_bf16(afr, vf, o[ct], 0, 0, 0);
            }
        }
    }

    if (qt < 4) {
        // single chunk: final output, fp32 (64-B segments per (r,ct) group)
        float* outp = out + (bT + qbase) * C_DIM;
        #pragma unroll
        for (int r = 0; r < 4; ++r) {
            float inv = 1.0f / l[r];
            #pragma unroll
            for (int ct = 0; ct < 8; ++ct)
                outp[(size_t)(quad * 4 + r) * C_DIM + ct * 16 + n16] = o[ct][r] * inv;
        }
    } else {
        // partial: stage bf16 in per-wave LDS, then full-line uint4 stores
        const int slot = b * 140 + chunk_base4(qt) + chunk;
        unsigned short* os = OS[w];
        #pragma unroll
        for (int ct = 0; ct < 8; ++ct)
            #pragma unroll
            for (int r = 0; r < 4; ++r)
                os[(quad * 4 + r) * 128 + ct * 16 + n16] = f2bf(o[ct][r]);
        unsigned short* op = opart + (size_t)slot * 8192 + w * 16 * 128;
        #pragma unroll
        for (int i = 0; i < 4; ++i) {
            int e = (lane + i * 64) * 8;   // 2048 shorts contiguous
            *reinterpret_cast<uint4*>(op + e) =
                *reinterpret_cast<const uint4*>(os + e);
        }
        if (n16 == 0) {
            #pragma unroll
            for (int r = 0; r < 4; ++r)
                mlbuf[(size_t)slot * 64 + w * 16 + quad * 4 + r] =
                    make_float2(m[r], l[r]);
        }
    }
}

// ---------------------------------------------------------------------------
// merge: combine <=8 bf16 partials per (b, qt>=4). grid (28, 8), block 256.
// ---------------------------------------------------------------------------
__global__ __launch_bounds__(256) void merge_kernel(
    const unsigned short* __restrict__ opart, const float2* __restrict__ mlbuf,
    float* __restrict__ out)
{
    const int qt = 4 + blockIdx.x;
    const int b  = blockIdx.y;
    const int nch  = (qt >> 2) + 1;
    const int base = b * 140 + chunk_base4(qt);
    const int row = threadIdx.x >> 2;
    const int c0  = (threadIdx.x & 3) * 32;

    float mi[8], li[8], wgt[8];
    float M = -INFINITY;
    for (int i = 0; i < nch; ++i) {
        float2 t = mlbuf[(size_t)(base + i) * 64 + row];
        mi[i] = t.x; li[i] = t.y;
        M = fmaxf(M, t.x);
    }
    float L = 0.f;
    for (int i = 0; i < nch; ++i) {
        wgt[i] = __expf(mi[i] - M);
        L += li[i] * wgt[i];
    }
    const float inv = 1.0f / L;

    float acc[32];
    #pragma unroll
    for (int j = 0; j < 32; ++j) acc[j] = 0.f;
    for (int i = 0; i < nch; ++i) {
        const unsigned short* op = opart + (size_t)(base + i) * 8192 + row * 128 + c0;
        const float wg = wgt[i];
        #pragma unroll
        for (int j4 = 0; j4 < 4; ++j4) {
            uint4 u = *reinterpret_cast<const uint4*>(op + j4 * 8);
            unsigned int vals[4] = {u.x, u.y, u.z, u.w};
            #pragma unroll
            for (int h = 0; h < 4; ++h) {
                union { unsigned int u; float f; } lo, hi;
                lo.u = (vals[h] & 0xFFFFu) << 16;
                hi.u = vals[h] & 0xFFFF0000u;
                acc[j4 * 8 + h * 2]     += wg * lo.f;
                acc[j4 * 8 + h * 2 + 1] += wg * hi.f;
            }
        }
    }
    float* orow = out + ((size_t)(b * T_SEQ + qt * 64 + row)) * C_DIM + c0;
    #pragma unroll
    for (int j4 = 0; j4 < 8; ++j4) {
        float4 r4;
        r4.x = acc[j4 * 4]     * inv;
        r4.y = acc[j4 * 4 + 1] * inv;
        r4.z = acc[j4 * 4 + 2] * inv;
        r4.w = acc[j4 * 4 + 3] * inv;
        *reinterpret_cast<float4*>(orow + j4 * 4) = r4;
    }
}

extern "C" void kernel_launch(void* const* d_in, const int* in_sizes, int n_in,
                              void* d_out, int out_size, void* d_ws, size_t ws_size,
                              hipStream_t stream) {
    const float* x  = (const float*)d_in[0];
    const float* Wk = (const float*)d_in[1];
    const float* Wq = (const float*)d_in[2];
    const float* Wv = (const float*)d_in[3];

    unsigned short* qw    = (unsigned short*)d_ws;
    unsigned short* kw    = qw + 2097152;
    unsigned short* vw    = kw + 2097152;
    unsigned short* opart = vw + 2097152;
    float2*         mlb   = (float2*)((char*)d_ws + ML_OFF);

    proj_kernel<<<dim3(256, 3), 256, 0, stream>>>(x, Wq, Wk, Wv, qw, kw, vw);
    attn_kernel<<<dim3(32, 8, 8), 256, 0, stream>>>(qw, kw, vw, opart, mlb, (float*)d_out);
    merge_kernel<<<dim3(28, 8), 256, 0, stream>>>(opart, mlb, (float*)d_out);
}

// Round 5
// 150.628 us; speedup vs baseline: 1.4829x; 1.4829x over previous
//
#include <hip/hip_runtime.h>

#define T_SEQ 2048
#define C_DIM 128
#define S_QK 0.08838834764831845f

typedef __attribute__((ext_vector_type(8))) short bf16x8;
typedef __attribute__((ext_vector_type(4))) float f32x4;

// ---- workspace layout ----
// qw  bf16 [8][2048][128]    @ 0
// kw  bf16 [8][2048][128]    @ 4,194,304
// vw  bf16 [8][128][2048]    @ 8,388,608   (V^T)
// opart bf16 [1120][64][128] @ 12,582,912  (18,350,080 B)
// ml  float2 [1120][64]      @ 30,932,992  (573,440 B)    total ~31.5 MB
#define ML_OFF 30932992UL

__device__ __forceinline__ unsigned short f2bf(float f) {
    union { float f; unsigned int u; } v; v.f = f;
    unsigned int r = v.u + 0x7FFFu + ((v.u >> 16) & 1u);
    return (unsigned short)(r >> 16);
}

// slot base within a batch for qt>=4, chunks of 4 key-tiles (140 slots/batch)
__device__ __forceinline__ int chunk_base4(int qt) {
    int g = qt >> 2;                       // 1..7
    return 2 * (g - 1) * (g + 2) + (qt - 4 * g) * (g + 1);
}

// ---------------------------------------------------------------------------
// proj: z-fused. One block does q,k,vT for its 64-row tile. Grid 256 (1D),
// linear id = b + 8*tile so all blocks of batch b share an XCD (i%8 heuristic).
// x staged once; W staged per z into Wl; epilogue staged in Wl after compute.
// ---------------------------------------------------------------------------
__global__ __launch_bounds__(256) void proj_kernel(
    const float* __restrict__ x,
    const float* __restrict__ Wq, const float* __restrict__ Wk,
    const float* __restrict__ Wv,
    unsigned short* __restrict__ qo, unsigned short* __restrict__ ko,
    unsigned short* __restrict__ vto)
{
    const int bid  = blockIdx.x;
    const int b    = bid & 7;
    const int tile = bid >> 3;             // 0..31 within batch
    const int rt   = b * 32 + tile;        // 64-row tile over B*T
    const int tid  = threadIdx.x;
    const int lane = tid & 63;
    const int w    = tid >> 6;
    const int n16  = lane & 15;
    const int quad = lane >> 4;

    __shared__ __align__(16) unsigned short Wl[128 * 136];   // 34816 B (also epilogue stage)
    __shared__ __align__(16) unsigned short Xl[64 * 136];    // 17408 B

    // ---- stage x tile once (fp32 -> bf16) ----
    const float* xr = x + (size_t)rt * 64 * C_DIM;
    #pragma unroll
    for (int i = 0; i < 8; ++i) {
        int e = (tid + i * 256) * 4;
        int r = e >> 7, c = e & 127;
        float4 v = *reinterpret_cast<const float4*>(xr + e);
        ushort4 o4;
        o4.x = f2bf(v.x); o4.y = f2bf(v.y); o4.z = f2bf(v.z); o4.w = f2bf(v.w);
        *reinterpret_cast<ushort4*>(&Xl[r * 136 + c]) = o4;
    }

    for (int z = 0; z < 3; ++z) {
        if (z) __syncthreads();            // prev epilogue's Wl reads done
        const float* W = (z == 0) ? Wq : (z == 1) ? Wk : Wv;
        const float scale = (z == 0) ? S_QK : 1.0f;
        #pragma unroll
        for (int i = 0; i < 16; ++i) {
            int e = (tid + i * 256) * 4;
            int r = e >> 7, c = e & 127;
            float4 v = *reinterpret_cast<const float4*>(W + e);
            ushort4 o4;
            o4.x = f2bf(v.x * scale); o4.y = f2bf(v.y * scale);
            o4.z = f2bf(v.z * scale); o4.w = f2bf(v.w * scale);
            *reinterpret_cast<ushort4*>(&Wl[r * 136 + c]) = o4;
        }
        __syncthreads();                   // W (and x, for z=0) visible

        bf16x8 afr[4];
        #pragma unroll
        for (int kk = 0; kk < 4; ++kk)
            afr[kk] = *reinterpret_cast<const bf16x8*>(
                &Xl[(w * 16 + n16) * 136 + kk * 32 + quad * 8]);

        f32x4 acc[8];
        #pragma unroll
        for (int nt = 0; nt < 8; ++nt) acc[nt] = (f32x4){0.f, 0.f, 0.f, 0.f};
        #pragma unroll
        for (int kk = 0; kk < 4; ++kk)
            #pragma unroll
            for (int nt = 0; nt < 8; ++nt) {
                bf16x8 bfr = *reinterpret_cast<const bf16x8*>(
                    &Wl[(nt * 16 + n16) * 136 + kk * 32 + quad * 8]);
                acc[nt] = __builtin_amdgcn_mfma_f32_16x16x32_bf16(afr[kk], bfr, acc[nt], 0, 0, 0);
            }
        __syncthreads();                   // all waves done reading Wl

        if (z < 2) {
            unsigned short* os = Wl + w * 2048;   // per-wave 16x128 stage
            #pragma unroll
            for (int nt = 0; nt < 8; ++nt)
                #pragma unroll
                for (int r = 0; r < 4; ++r)
                    os[(quad * 4 + r) * 128 + nt * 16 + n16] = f2bf(acc[nt][r]);
            unsigned short* dst = (z == 0 ? qo : ko) + (size_t)(rt * 64 + w * 16) * C_DIM;
            #pragma unroll
            for (int i = 0; i < 4; ++i) {
                int e = (lane + i * 64) * 8;
                *reinterpret_cast<uint4*>(dst + e) =
                    *reinterpret_cast<const uint4*>(os + e);
            }
        } else {
            unsigned short* os = Wl + w * 3072;   // per-wave [128 d][16 t], stride 24
            #pragma unroll
            for (int nt = 0; nt < 8; ++nt)
                #pragma unroll
                for (int r = 0; r < 4; ++r)
                    os[(nt * 16 + n16) * 24 + quad * 4 + r] = f2bf(acc[nt][r]);
            unsigned short* dst = vto + (size_t)b * C_DIM * T_SEQ + tile * 64 + w * 16;
            #pragma unroll
            for (int i = 0; i < 4; ++i) {
                int e = lane + i * 64;            // (d, half): 128 x 2
                int d = e >> 1, half = (e & 1) * 8;
                *reinterpret_cast<uint4*>(dst + (size_t)d * T_SEQ + half) =
                    *reinterpret_cast<const uint4*>(os + d * 24 + half);
            }
        }
    }
}

// ---------------------------------------------------------------------------
// attn pass 1: split-K flash attention, LDS-staged K/V with register
// prefetch. Grid 2048 (1D): id = b + 8*(qt + 32*chunk) -> batch pinned to XCD.
// chunk = 4 key-tiles. qt<4 writes final output; else bf16 partial + (m,l).
// ---------------------------------------------------------------------------
__global__ __launch_bounds__(256) void attn_kernel(
    const unsigned short* __restrict__ qb,
    const unsigned short* __restrict__ kb,
    const unsigned short* __restrict__ vtb,
    unsigned short* __restrict__ opart, float2* __restrict__ mlbuf,
    float* __restrict__ out)
{
    const int bid   = blockIdx.x;
    const int b     = bid & 7;
    const int t2    = bid >> 3;
    const int qt    = t2 & 31;
    const int chunk = t2 >> 5;
    if (chunk * 4 > qt) return;

    const int tid  = threadIdx.x;
    const int lane = tid & 63;
    const int w    = tid >> 6;
    const int n16  = lane & 15;
    const int quad = lane >> 4;

    __shared__ __align__(16) unsigned short Kl[64 * 136];    // 17408 B
    __shared__ __align__(16) unsigned short Vl[128 * 72];    // 18432 B
    __shared__ __align__(16) unsigned short Pl[4][16 * 72];  //  9216 B (P + epilogue stage)

    const size_t bT = (size_t)b * T_SEQ;
    const int qbase = qt * 64 + w * 16;

    bf16x8 qfr[4];
    #pragma unroll
    for (int kk = 0; kk < 4; ++kk)
        qfr[kk] = *reinterpret_cast<const bf16x8*>(
            qb + (bT + qbase + n16) * C_DIM + kk * 32 + quad * 8);

    f32x4 o[8];
    #pragma unroll
    for (int ct = 0; ct < 8; ++ct) o[ct] = (f32x4){0.f, 0.f, 0.f, 0.f};
    float m[4], l[4];
    #pragma unroll
    for (int r = 0; r < 4; ++r) { m[r] = -INFINITY; l[r] = 0.f; }

    const int k0 = chunk * 4;
    const int k1 = min(k0 + 4, qt + 1);
    const unsigned short* vbase = vtb + (size_t)b * C_DIM * T_SEQ;

    // ---- prologue: tile k0 -> registers ----
    uint4 kreg[4], vreg[4];
    {
        const unsigned short* ks = kb + (bT + (size_t)k0 * 64) * C_DIM;
        #pragma unroll
        for (int i = 0; i < 4; ++i) {
            int e = tid + i * 256;
            kreg[i] = *reinterpret_cast<const uint4*>(ks + (e >> 4) * 128 + (e & 15) * 8);
        }
        const unsigned short* vs = vbase + (size_t)k0 * 64;
        #pragma unroll
        for (int i = 0; i < 4; ++i) {
            int e = tid + i * 256;
            vreg[i] = *reinterpret_cast<const uint4*>(vs + (size_t)(e >> 3) * T_SEQ + (e & 7) * 8);
        }
    }

    for (int kt = k0; kt < k1; ++kt) {
        __syncthreads();                   // prev iter's LDS reads done
        #pragma unroll
        for (int i = 0; i < 4; ++i) {
            int e = tid + i * 256;
            *reinterpret_cast<uint4*>(&Kl[(e >> 4) * 136 + (e & 15) * 8]) = kreg[i];
        }
        #pragma unroll
        for (int i = 0; i < 4; ++i) {
            int e = tid + i * 256;
            *reinterpret_cast<uint4*>(&Vl[(e >> 3) * 72 + (e & 7) * 8]) = vreg[i];
        }
        __syncthreads();

        // prefetch next tile (covered by compute below)
        if (kt + 1 < k1) {
            const unsigned short* ks = kb + (bT + (size_t)(kt + 1) * 64) * C_DIM;
            #pragma unroll
            for (int i = 0; i < 4; ++i) {
                int e = tid + i * 256;
                kreg[i] = *reinterpret_cast<const uint4*>(ks + (e >> 4) * 128 + (e & 15) * 8);
            }
            const unsigned short* vs = vbase + (size_t)(kt + 1) * 64;
            #pragma unroll
            for (int i = 0; i < 4; ++i) {
                int e = tid + i * 256;
                vreg[i] = *reinterpret_cast<const uint4*>(vs + (size_t)(e >> 3) * T_SEQ + (e & 7) * 8);
            }
        }

        // ---- S = Q K^T ----
        f32x4 s[4];
        #pragma unroll
        for (int nt = 0; nt < 4; ++nt) s[nt] = (f32x4){0.f, 0.f, 0.f, 0.f};
        #pragma unroll
        for (int kk = 0; kk < 4; ++kk)
            #pragma unroll
            for (int nt = 0; nt < 4; ++nt) {
                bf16x8 kf = *reinterpret_cast<const bf16x8*>(
                    &Kl[(nt * 16 + n16) * 136 + kk * 32 + quad * 8]);
                s[nt] = __builtin_amdgcn_mfma_f32_16x16x32_bf16(qfr[kk], kf, s[nt], 0, 0, 0);
            }

        if (kt == qt) {                    // causal mask on diagonal tile
            #pragma unroll
            for (int nt = 0; nt < 4; ++nt)
                #pragma unroll
                for (int r = 0; r < 4; ++r) {
                    int sabs = kt * 64 + nt * 16 + n16;
                    int qabs = qbase + quad * 4 + r;
                    if (sabs > qabs) s[nt][r] = -1e30f;
                }
        }

        // ---- online softmax ----
        float alpha[4];
        #pragma unroll
        for (int r = 0; r < 4; ++r) {
            float tmax = fmaxf(fmaxf(s[0][r], s[1][r]), fmaxf(s[2][r], s[3][r]));
            #pragma unroll
            for (int off = 1; off < 16; off <<= 1)
                tmax = fmaxf(tmax, __shfl_xor(tmax, off));
            float mn = fmaxf(m[r], tmax);
            alpha[r] = __expf(m[r] - mn);
            float tsum = 0.f;
            #pragma unroll
            for (int nt = 0; nt < 4; ++nt) {
                float p = __expf(s[nt][r] - mn);
                s[nt][r] = p;
                tsum += p;
            }
            #pragma unroll
            for (int off = 1; off < 16; off <<= 1)
                tsum += __shfl_xor(tsum, off);
            l[r] = l[r] * alpha[r] + tsum;
            m[r] = mn;
        }
        #pragma unroll
        for (int ct = 0; ct < 8; ++ct)
            #pragma unroll
            for (int r = 0; r < 4; ++r)
                o[ct][r] *= alpha[r];

        // ---- P: C-layout -> per-wave LDS -> A-layout ----
        unsigned short* pw = Pl[w];
        #pragma unroll
        for (int nt = 0; nt < 4; ++nt)
            #pragma unroll
            for (int r = 0; r < 4; ++r)
                pw[(quad * 4 + r) * 72 + nt * 16 + n16] = f2bf(s[nt][r]);

        // ---- O += P V ----
        #pragma unroll
        for (int kk2 = 0; kk2 < 2; ++kk2) {
            bf16x8 afr = *reinterpret_cast<const bf16x8*>(
                &pw[n16 * 72 + kk2 * 32 + quad * 8]);
            #pragma unroll
            for (int ct = 0; ct < 8; ++ct) {
                bf16x8 vf = *reinterpret_cast<const bf16x8*>(
                    &Vl[(ct * 16 + n16) * 72 + kk2 * 32 + quad * 8]);
                o[ct] = __builtin_amdgcn_mfma_f32_16x16x32_bf16(afr, vf, o[ct], 0, 0, 0);
            }
        }
    }

    if (qt < 4) {
        // single chunk: final fp32 output (64-B segments, full sectors)
        float* outp = out + (bT + qbase) * C_DIM;
        #pragma unroll
        for (int r = 0; r < 4; ++r) {
            float inv = 1.0f / l[r];
            #pragma unroll
            for (int ct = 0; ct < 8; ++ct)
                outp[(size_t)(quad * 4 + r) * C_DIM + ct * 16 + n16] = o[ct][r] * inv;
        }
    } else {
        // partial: stage through per-wave Pl in two 64-col halves,
        // then full-row 128-B uint4 stores (no sub-sector write amplification)
        const int slot = b * 140 + chunk_base4(qt) + chunk;
        unsigned short* op = opart + (size_t)slot * 8192 + w * 16 * 128;
        unsigned short* pw = Pl[w];
        #pragma unroll
        for (int h = 0; h < 2; ++h) {
            #pragma unroll
            for (int c4 = 0; c4 < 4; ++c4)       // ct = 4h + c4
                #pragma unroll
                for (int r = 0; r < 4; ++r)
                    pw[(quad * 4 + r) * 72 + c4 * 16 + n16] = f2bf(o[4 * h + c4][r]);
            #pragma unroll
            for (int i = 0; i < 2; ++i) {
                int e = lane + i * 64;           // 128 chunks: row=e>>3, seg=e&7
                int row = e >> 3, seg = e & 7;
                *reinterpret_cast<uint4*>(op + row * 128 + h * 64 + seg * 8) =
                    *reinterpret_cast<const uint4*>(pw + row * 72 + seg * 8);
            }
        }
        if (n16 == 0) {
            #pragma unroll
            for (int r = 0; r < 4; ++r)
                mlbuf[(size_t)slot * 64 + w * 16 + quad * 4 + r] =
                    make_float2(m[r], l[r]);
        }
    }
}

// ---------------------------------------------------------------------------
// merge: combine <=8 bf16 partials per (b, qt>=4). Grid 224 (1D), batch-pinned.
// ---------------------------------------------------------------------------
__global__ __launch_bounds__(256) void merge_kernel(
    const unsigned short* __restrict__ opart, const float2* __restrict__ mlbuf,
    float* __restrict__ out)
{
    const int bid = blockIdx.x;
    const int b   = bid & 7;
    const int qt  = 4 + (bid >> 3);
    const int nch  = (qt >> 2) + 1;
    const int base = b * 140 + chunk_base4(qt);
    const int row = threadIdx.x >> 2;
    const int c0  = (threadIdx.x & 3) * 32;

    float mi[8], li[8], wgt[8];
    float M = -INFINITY;
    for (int i = 0; i < nch; ++i) {
        float2 t = mlbuf[(size_t)(base + i) * 64 + row];
        mi[i] = t.x; li[i] = t.y;
        M = fmaxf(M, t.x);
    }
    float L = 0.f;
    for (int i = 0; i < nch; ++i) {
        wgt[i] = __expf(mi[i] - M);
        L += li[i] * wgt[i];
    }
    const float inv = 1.0f / L;

    float acc[32];
    #pragma unroll
    for (int j = 0; j < 32; ++j) acc[j] = 0.f;
    for (int i = 0; i < nch; ++i) {
        const unsigned short* op = opart + (size_t)(base + i) * 8192 + row * 128 + c0;
        const float wg = wgt[i];
        #pragma unroll
        for (int j4 = 0; j4 < 4; ++j4) {
            uint4 u = *reinterpret_cast<const uint4*>(op + j4 * 8);
            unsigned int vals[4] = {u.x, u.y, u.z, u.w};
            #pragma unroll
            for (int h = 0; h < 4; ++h) {
                union { unsigned int u; float f; } lo, hi;
                lo.u = (vals[h] & 0xFFFFu) << 16;
                hi.u = vals[h] & 0xFFFF0000u;
                acc[j4 * 8 + h * 2]     += wg * lo.f;
                acc[j4 * 8 + h * 2 + 1] += wg * hi.f;
            }
        }
    }
    float* orow = out + ((size_t)(b * T_SEQ + qt * 64 + row)) * C_DIM + c0;
    #pragma unroll
    for (int j4 = 0; j4 < 8; ++j4) {
        float4 r4;
        r4.x = acc[j4 * 4]     * inv;
        r4.y = acc[j4 * 4 + 1] * inv;
        r4.z = acc[j4 * 4 + 2] * inv;
        r4.w = acc[j4 * 4 + 3] * inv;
        *reinterpret_cast<float4*>(orow + j4 * 4) = r4;
    }
}

extern "C" void kernel_launch(void* const* d_in, const int* in_sizes, int n_in,
                              void* d_out, int out_size, void* d_ws, size_t ws_size,
                              hipStream_t stream) {
    const float* x  = (const float*)d_in[0];
    const float* Wk = (const float*)d_in[1];
    const float* Wq = (const float*)d_in[2];
    const float* Wv = (const float*)d_in[3];

    unsigned short* qw    = (unsigned short*)d_ws;
    unsigned short* kw    = qw + 2097152;
    unsigned short* vw    = kw + 2097152;
    unsigned short* opart = vw + 2097152;
    float2*         mlb   = (float2*)((char*)d_ws + ML_OFF);

    proj_kernel<<<256, 256, 0, stream>>>(x, Wq, Wk, Wv, qw, kw, vw);
    attn_kernel<<<2048, 256, 0, stream>>>(qw, kw, vw, opart, mlb, (float*)d_out);
    merge_kernel<<<224, 256, 0, stream>>>(opart, mlb, (float*)d_out);
}